// Round 5
// baseline (284.623 us; speedup 1.0000x reference)
//
#include <hip/hip_runtime.h>
#include <hip/hip_bf16.h>
#include <stdint.h>

typedef __bf16 bf16x8 __attribute__((ext_vector_type(8)));
typedef unsigned short ushort8 __attribute__((ext_vector_type(8)));
typedef unsigned short ushort4v __attribute__((ext_vector_type(4)));
typedef float f32x4 __attribute__((ext_vector_type(4)));

#define MFMA16(a, b, c) __builtin_amdgcn_mfma_f32_16x16x32_bf16((a), (b), (c), 0, 0, 0)

__device__ __forceinline__ unsigned short f2bf(float f) {
    uint32_t u = __float_as_uint(f);
    u += 0x7FFFu + ((u >> 16) & 1u);   // round-to-nearest-even
    return (unsigned short)(u >> 16);
}

// ------- kernel 1: pack Wt[640][512] = [W1|W2|W3]^T in bf16 (B-operand) ------
__global__ void k_build_wt(const float* __restrict__ W1, const float* __restrict__ W2,
                           const float* __restrict__ W3, unsigned short* __restrict__ Wt) {
    int idx = blockIdx.x * 256 + threadIdx.x;     // 0 .. 327679
    int n = idx >> 9;                              // output col 0..639
    int k = idx & 511;                             // input channel
    float v;
    if (n < 64)       v = W1[k * 64 + n];
    else if (n < 128) v = W2[k * 64 + (n - 64)];
    else              v = W3[k * 512 + (n - 128)];
    Wt[idx] = f2bf(v);
}

// -------- kernel 2: QKV projection GEMM, M=16384 K=512 N=640 (bf16 MFMA) -----
// m-tile 32 (512 blocks). 8 waves x 80 N-cols (5 x 16-tiles). Register-lean:
// B-frags loaded per (k,nt) (L2-hot, 640 KB Wt), peak ~100 regs -> 4 waves/EU.
__global__ __launch_bounds__(512, 4) void k_proj(const float* __restrict__ x,
                                                 const unsigned short* __restrict__ Wt,
                                                 unsigned short* __restrict__ Qb,
                                                 unsigned short* __restrict__ Kb,
                                                 unsigned short* __restrict__ Vt) {
    __shared__ __align__(16) unsigned short As[32 * 520];
    const int tid  = threadIdx.x;
    const int lane = tid & 63;
    const int w    = tid >> 6;
    const int m0   = blockIdx.x * 32;
    const int col  = lane & 15, quad = lane >> 4;

    // stage A tile: 32 rows x 512 ch, convert fp32 -> bf16
#pragma unroll
    for (int itr = 0; itr < 8; ++itr) {
        int idx = itr * 512 + tid;
        int row = idx >> 7, c4 = (idx & 127) << 2;
        f32x4 v = *(const f32x4*)(x + (m0 + row) * 512 + c4);
        ushort4v o;
        o[0] = f2bf(v[0]); o[1] = f2bf(v[1]); o[2] = f2bf(v[2]); o[3] = f2bf(v[3]);
        *(ushort4v*)(&As[row * 520 + c4]) = o;
    }
    __syncthreads();

    f32x4 acc[2][5] = {};
    const unsigned short* bp = Wt + quad * 8;

    for (int k = 0; k < 16; ++k) {
        bf16x8 af[2];
#pragma unroll
        for (int it = 0; it < 2; ++it)
            af[it] = *(const bf16x8*)(&As[(it * 16 + col) * 520 + k * 32 + quad * 8]);
#pragma unroll
        for (int nt = 0; nt < 5; ++nt) {
            bf16x8 bf = *(const bf16x8*)(bp + (w * 80 + nt * 16 + col) * 512 + k * 32);
#pragma unroll
            for (int it = 0; it < 2; ++it)
                acc[it][nt] = MFMA16(af[it], bf, acc[it][nt]);
        }
    }

#pragma unroll
    for (int nt = 0; nt < 5; ++nt) {
        int n0 = w * 80 + nt * 16;                 // wave-uniform
        if (n0 < 128) {                            // Q or K slab
            unsigned short* dst = (n0 < 64) ? Qb : Kb;
            int nc = (n0 < 64) ? (n0 + col) : (n0 - 64 + col);
#pragma unroll
            for (int it = 0; it < 2; ++it) {
                int ig = m0 + it * 16 + quad * 4;
#pragma unroll
                for (int r = 0; r < 4; ++r)
                    dst[(ig + r) * 64 + nc] = f2bf(acc[it][nt][r]);
            }
        } else {                                   // V slab -> transposed Vt[c][i]
            int vrow = n0 - 128 + col;
#pragma unroll
            for (int it = 0; it < 2; ++it) {
                int ig = m0 + it * 16 + quad * 4;
                int b = ig >> 12, ii = ig & 4095;
                ushort4v pk;
#pragma unroll
                for (int r = 0; r < 4; ++r) pk[r] = f2bf(acc[it][nt][r]);
                *(ushort4v*)(Vt + ((b * 512 + vrow) << 12) + ii) = pk;
            }
        }
    }
}

// ---------------- kernel 3: flash attention, full j-loop, fused epilogue -----
// 512 WGs: bx&3 -> batch, (bx>>2)&1 -> channel half, bx>>3 -> 64-row Q tile.
// Each XCD (bx&7) owns one (b,chalf): K 0.5 MB + V-half 2 MB -> L2-resident.
// Wave w owns 32 V-channels. acc[4][2]; online softmax completes in-block;
// epilogue normalizes, applies gamma, adds residual, writes out directly.
__global__ __launch_bounds__(512, 4) void k_flash(const unsigned short* __restrict__ Qb,
                                                  const unsigned short* __restrict__ Kb,
                                                  const unsigned short* __restrict__ Vt,
                                                  const float* __restrict__ x,
                                                  const float* __restrict__ gamma,
                                                  float* __restrict__ out) {
    __shared__ __align__(16) unsigned short Qs[64 * 72];
    __shared__ __align__(16) float          Ss[64 * 132];
    __shared__ __align__(16) unsigned short Ps[64 * 136];
    __shared__ float m_s[64], l_s[64], al_s[64];

    const int tid   = threadIdx.x;
    const int lane  = tid & 63;
    const int w     = tid >> 6;
    const int col   = lane & 15, quad = lane >> 4;
    const int b     = blockIdx.x & 3;
    const int chalf = (blockIdx.x >> 2) & 1;
    const int i0    = (blockIdx.x >> 3) * 64;

    const unsigned short* Qbase = Qb + (b * 4096 + i0) * 64;
    const unsigned short* Kbase = Kb + b * 4096 * 64;
    const unsigned short* Vbase = Vt + (b * 512 + chalf * 256 + w * 32) * 4096;

    if (tid < 64) { m_s[tid] = -3.0e38f; l_s[tid] = 0.0f; }
    {   // stage Q tile (coalesced 16B per thread)
        int row = tid >> 3, ch = tid & 7;
        *(ushort8*)(&Qs[row * 72 + ch * 8]) = *(const ushort8*)(Qbase + row * 64 + ch * 8);
    }
    __syncthreads();

    f32x4 acc[4][2] = {};

    for (int jj = 0; jj < 32; ++jj) {
        const int j0 = jj * 128;
        // prefetch V B-fragments (wave's 32 channels) for the PV stage
        bf16x8 vf[2][4];
#pragma unroll
        for (int ct = 0; ct < 2; ++ct) {
            const unsigned short* vp = Vbase + (ct * 16 + col) * 4096 + j0 + quad * 8;
#pragma unroll
            for (int kk = 0; kk < 4; ++kk) vf[ct][kk] = *(const bf16x8*)(vp + kk * 32);
        }
        // ---- S = Q.K^T : wave w computes score cols [j0+16w, j0+16w+16) ----
        {
            const unsigned short* kp = Kbase + (j0 + w * 16 + col) * 64 + quad * 8;
            bf16x8 kf0 = *(const bf16x8*)(kp);
            bf16x8 kf1 = *(const bf16x8*)(kp + 32);
#pragma unroll
            for (int it = 0; it < 4; ++it) {
                bf16x8 qf0 = *(const bf16x8*)(&Qs[(it * 16 + col) * 72 + quad * 8]);
                bf16x8 qf1 = *(const bf16x8*)(&Qs[(it * 16 + col) * 72 + 32 + quad * 8]);
                f32x4 s = {};
                s = MFMA16(qf0, kf0, s);
                s = MFMA16(qf1, kf1, s);
                int rb = it * 16 + quad * 4;
#pragma unroll
                for (int r = 0; r < 4; ++r) Ss[(rb + r) * 132 + w * 16 + col] = s[r];
            }
        }
        __syncthreads();
        // ---- online softmax over the 64x128 tile (8 threads per row) ----
        {
            int row = tid >> 3, g = tid & 7;
            float* sp = &Ss[row * 132 + g * 16];
            f32x4 v0 = *(f32x4*)(sp + 0);
            f32x4 v1 = *(f32x4*)(sp + 4);
            f32x4 v2 = *(f32x4*)(sp + 8);
            f32x4 v3 = *(f32x4*)(sp + 12);
            float mx = fmaxf(fmaxf(fmaxf(v0[0], v0[1]), fmaxf(v0[2], v0[3])),
                             fmaxf(fmaxf(v1[0], v1[1]), fmaxf(v1[2], v1[3])));
            mx = fmaxf(mx, fmaxf(fmaxf(fmaxf(v2[0], v2[1]), fmaxf(v2[2], v2[3])),
                                 fmaxf(fmaxf(v3[0], v3[1]), fmaxf(v3[2], v3[3]))));
            mx = fmaxf(mx, __shfl_xor(mx, 1, 8));
            mx = fmaxf(mx, __shfl_xor(mx, 2, 8));
            mx = fmaxf(mx, __shfl_xor(mx, 4, 8));
            float mo = m_s[row];
            float mn = fmaxf(mo, mx);
            float al = __expf(mo - mn);
            f32x4 e0, e1, e2, e3;
#pragma unroll
            for (int i = 0; i < 4; ++i) {
                e0[i] = __expf(v0[i] - mn); e1[i] = __expf(v1[i] - mn);
                e2[i] = __expf(v2[i] - mn); e3[i] = __expf(v3[i] - mn);
            }
            float sum = (e0[0]+e0[1]+e0[2]+e0[3]) + (e1[0]+e1[1]+e1[2]+e1[3])
                      + (e2[0]+e2[1]+e2[2]+e2[3]) + (e3[0]+e3[1]+e3[2]+e3[3]);
            ushort8 p0, p1;
#pragma unroll
            for (int i = 0; i < 4; ++i) {
                p0[i]     = f2bf(e0[i]); p0[i + 4] = f2bf(e1[i]);
                p1[i]     = f2bf(e2[i]); p1[i + 4] = f2bf(e3[i]);
            }
            *(ushort8*)(&Ps[row * 136 + g * 16])     = p0;
            *(ushort8*)(&Ps[row * 136 + g * 16 + 8]) = p1;
            sum += __shfl_xor(sum, 1, 8);
            sum += __shfl_xor(sum, 2, 8);
            sum += __shfl_xor(sum, 4, 8);
            if (g == 0) { m_s[row] = mn; l_s[row] = al * l_s[row] + sum; al_s[row] = al; }
        }
        __syncthreads();
        // ---- rescale O and accumulate P.V (wave's 32 V-cols) ----
#pragma unroll
        for (int it = 0; it < 4; ++it) {
            int rb = it * 16 + quad * 4;
            f32x4 av;
            av[0] = al_s[rb]; av[1] = al_s[rb + 1]; av[2] = al_s[rb + 2]; av[3] = al_s[rb + 3];
#pragma unroll
            for (int ct = 0; ct < 2; ++ct) acc[it][ct] *= av;
        }
#pragma unroll
        for (int it = 0; it < 4; ++it) {
            bf16x8 pf[4];
#pragma unroll
            for (int kk = 0; kk < 4; ++kk)
                pf[kk] = *(const bf16x8*)(&Ps[(it * 16 + col) * 136 + kk * 32 + quad * 8]);
#pragma unroll
            for (int ct = 0; ct < 2; ++ct)
#pragma unroll
                for (int kk = 0; kk < 4; ++kk)
                    acc[it][ct] = MFMA16(pf[kk], vf[ct][kk], acc[it][ct]);
        }
    }

    // ---- epilogue: out[f] = gamma*O[i,c]/l + x[f], f = c*4096 + i (raw reshape) ----
    const float gam = gamma[0];
    const float* xb_ = x + b * 2097152;
    float* ob_ = out + b * 2097152;
#pragma unroll
    for (int it = 0; it < 4; ++it) {
        int rb = it * 16 + quad * 4;
        f32x4 li;
        li[0] = 1.0f / l_s[rb];     li[1] = 1.0f / l_s[rb + 1];
        li[2] = 1.0f / l_s[rb + 2]; li[3] = 1.0f / l_s[rb + 3];
#pragma unroll
        for (int ct = 0; ct < 2; ++ct) {
            int cg = chalf * 256 + w * 32 + ct * 16 + col;
            int f = cg * 4096 + i0 + rb;          // 16B-aligned, r gives contiguous floats
            f32x4 xv = *(const f32x4*)(xb_ + f);
            f32x4 a = acc[it][ct];
            f32x4 o;
            o[0] = gam * a[0] * li[0] + xv[0];
            o[1] = gam * a[1] * li[1] + xv[1];
            o[2] = gam * a[2] * li[2] + xv[2];
            o[3] = gam * a[3] * li[3] + xv[3];
            *(f32x4*)(ob_ + f) = o;
        }
    }
}

extern "C" void kernel_launch(void* const* d_in, const int* in_sizes, int n_in,
                              void* d_out, int out_size, void* d_ws, size_t ws_size,
                              hipStream_t stream) {
    const float* x  = (const float*)d_in[0];
    const float* W1 = (const float*)d_in[1];
    const float* W2 = (const float*)d_in[2];
    const float* W3 = (const float*)d_in[3];
    const float* gm = (const float*)d_in[4];
    float* out = (float*)d_out;

    char* ws = (char*)d_ws;
    unsigned short* Wt = (unsigned short*)(ws);                    // 640 KiB @ 0
    unsigned short* Qb = (unsigned short*)(ws + (1u << 20));       // 2 MiB
    unsigned short* Kb = (unsigned short*)(ws + (3u << 20));       // 2 MiB
    unsigned short* Vt = (unsigned short*)(ws + (5u << 20));       // 16 MiB
    // total workspace use: 21 MiB

    hipLaunchKernelGGL(k_build_wt, dim3(1280), dim3(256), 0, stream, W1, W2, W3, Wt);
    hipLaunchKernelGGL(k_proj,     dim3(512),  dim3(512), 0, stream, x, Wt, Qb, Kb, Vt);
    hipLaunchKernelGGL(k_flash,    dim3(512),  dim3(512), 0, stream, Qb, Kb, Vt, x, gm, out);
}